// Round 14
// baseline (655.680 us; speedup 1.0000x reference)
//
#include <hip/hip_runtime.h>

#define N_NODES 50000
#define N_PAD   50048   // multiple of 64; pad rows garbage, never consumed
#define N_EDGES 800000
#define N_GRAPHS 500
#define DIM 128
#define EDIM 7
#define LAYERS 5
#define NCLASS 10
#define BN_EPS 1e-5f
#define TM 32           // GEMM tile rows: 1564 blocks -> ~8 blocks/CU (was 64 -> 3/CU)
#define AST 264         // LDS A row stride (ushort): 528 B = odd 16B multiple -> conflict-free b128
#define NSB ((N_NODES + 256) / 256)   // 196 scan blocks
#define NBA 16          // nodes per aggregate block (16 lanes/node, 8 feats/lane)

typedef __attribute__((ext_vector_type(8))) short bf16x8;
typedef __attribute__((ext_vector_type(4))) float f32x4;
typedef _Float16 h2 __attribute__((ext_vector_type(2)));

__device__ __forceinline__ unsigned short f2bf(float f) {
    unsigned u = __float_as_uint(f);
    u = u + 0x7fffu + ((u >> 16) & 1u);   // RNE
    return (unsigned short)(u >> 16);
}
__device__ __forceinline__ float bf2f(unsigned short h) {
    return __uint_as_float(((unsigned)h) << 16);
}
__device__ __forceinline__ h2 u2h2(unsigned u) {
    union { unsigned u; h2 h; } c; c.u = u; return c.h;
}
__device__ __forceinline__ unsigned h22u(h2 h) {
    union { h2 h; unsigned u; } c; c.h = h; return c.u;
}
__device__ __forceinline__ unsigned packh2(float a, float b) {
    h2 h; h.x = (_Float16)a; h.y = (_Float16)b;   // RNE casts
    return h22u(h);
}

// ---------------- CSR build ----------------

__global__ void zero_ints(int* __restrict__ p, int n) {
    int i = blockIdx.x * 256 + threadIdx.x;
    if (i < n) p[i] = 0;
}

__global__ void hist_kernel(const int* __restrict__ dst, int* __restrict__ deg) {
    int e = blockIdx.x * 256 + threadIdx.x;
    if (e < N_EDGES) atomicAdd(&deg[dst[e]], 1);
}

__global__ __launch_bounds__(256)
void scan1(const int* __restrict__ deg, int* __restrict__ ro, int* __restrict__ bsums) {
    __shared__ int ws[4];
    int t = threadIdx.x;
    int i = blockIdx.x * 256 + t;
    int v = (i < N_NODES) ? deg[i] : 0;
    int lane = t & 63, wv = t >> 6;
    int s = v;
    #pragma unroll
    for (int off = 1; off < 64; off <<= 1) {
        int u = __shfl_up(s, off, 64);
        if (lane >= off) s += u;
    }
    if (lane == 63) ws[wv] = s;
    __syncthreads();
    if (t == 0) {
        int a = 0;
        #pragma unroll
        for (int k = 0; k < 4; ++k) { int x = ws[k]; ws[k] = a; a += x; }
        bsums[blockIdx.x] = a;
    }
    __syncthreads();
    int excl = s - v + ws[wv];
    if (i <= N_NODES) ro[i] = excl;
}

__global__ __launch_bounds__(256)
void scan2(int* __restrict__ bsums) {
    __shared__ int ws[4];
    int t = threadIdx.x;
    int v = (t < NSB) ? bsums[t] : 0;
    int lane = t & 63, wv = t >> 6;
    int s = v;
    #pragma unroll
    for (int off = 1; off < 64; off <<= 1) {
        int u = __shfl_up(s, off, 64);
        if (lane >= off) s += u;
    }
    if (lane == 63) ws[wv] = s;
    __syncthreads();
    if (t == 0) {
        int a = 0;
        #pragma unroll
        for (int k = 0; k < 4; ++k) { int x = ws[k]; ws[k] = a; a += x; }
    }
    __syncthreads();
    if (t < NSB) bsums[t] = s - v + ws[wv];
}

__global__ __launch_bounds__(256)
void scan3(int* __restrict__ ro, const int* __restrict__ bsums, int* __restrict__ cursor) {
    int i = blockIdx.x * 256 + threadIdx.x;
    if (i <= N_NODES) {
        int r = ro[i] + bsums[i >> 8];
        ro[i] = r;
        if (i < N_NODES) cursor[i] = r;
    }
}

// single pass: sequential read of src/dst/edge_attr -> fp16, scatter to CSR slots.
__global__ void fill_rec(const int* __restrict__ dst, const int* __restrict__ src,
                         const float* __restrict__ edge_attr,
                         int* __restrict__ cursor,
                         uint4* __restrict__ ea16, int* __restrict__ srcc) {
    int e = blockIdx.x * 256 + threadIdx.x;
    if (e < N_EDGES) {
        const float* ap = edge_attr + (size_t)e * EDIM;
        uint4 ea;
        ea.x = packh2(ap[0], ap[1]);
        ea.y = packh2(ap[2], ap[3]);
        ea.z = packh2(ap[4], ap[5]);
        ea.w = packh2(ap[6], 0.f);
        int s = src[e];
        int pos = atomicAdd(&cursor[dst[e]], 1);
        ea16[pos] = ea;
        srcc[pos] = s;
    }
}

// ---------------- one-time preps ----------------

__global__ void init_x(float* __restrict__ x, unsigned short* __restrict__ xb,
                       const float* __restrict__ emb) {
    int i = blockIdx.x * 256 + threadIdx.x;
    if (i < N_NODES * DIM) {
        float v = emb[i & (DIM - 1)];
        x[i] = v;
        xb[i] = f2bf(v);
    }
}

// W [k][n] fp32 -> transposed hi/lo bf16 Wt[m][n][k]
__global__ void prep_w(const float* __restrict__ W1, const float* __restrict__ W2,
                       unsigned short* __restrict__ Wthi, unsigned short* __restrict__ Wtlo) {
    int i = blockIdx.x * 256 + threadIdx.x;
    if (i >= 2 * LAYERS * DIM * DIM) return;
    int m = i >> 14;
    int n = i & 127;
    int k = (i >> 7) & 127;
    const float* W = (m < LAYERS) ? (W1 + (size_t)m * DIM * DIM)
                                  : (W2 + (size_t)(m - LAYERS) * DIM * DIM);
    float v = W[k * DIM + n];
    unsigned short hi = f2bf(v);
    float lo = v - bf2f(hi);
    size_t o = ((size_t)m << 14) + (size_t)n * DIM + k;
    Wthi[o] = hi;
    Wtlo[o] = f2bf(lo);
}

// ---------------- aggregation (R12 structure: best measured, 53 us) ----------------
// 16 nodes/256-block, 16 lanes/node, 8 feats/lane; split ea16/srcc arrays.

#if __has_builtin(__builtin_amdgcn_fdot2)
#define HAVE_FDOT2 1
#else
#define HAVE_FDOT2 0
#endif

__device__ __forceinline__ void edge_accum8(float4& acc0, float4& acc1,
                                            uint4 eav, uint4 xv,
                                            const unsigned* Wp,
                                            const float4& b0, const float4& b1) {
    float el[8] = {b0.x, b0.y, b0.z, b0.w, b1.x, b1.y, b1.z, b1.w};
#if HAVE_FDOT2
    #pragma unroll
    for (int d = 0; d < 8; ++d) {
        float e = el[d];
        e = __builtin_amdgcn_fdot2(u2h2(eav.x), u2h2(Wp[d * 4 + 0]), e, false);
        e = __builtin_amdgcn_fdot2(u2h2(eav.y), u2h2(Wp[d * 4 + 1]), e, false);
        e = __builtin_amdgcn_fdot2(u2h2(eav.z), u2h2(Wp[d * 4 + 2]), e, false);
        e = __builtin_amdgcn_fdot2(u2h2(eav.w), u2h2(Wp[d * 4 + 3]), e, false);
        el[d] = e;
    }
#else
    h2 ea01 = u2h2(eav.x), ea23 = u2h2(eav.y), ea45 = u2h2(eav.z), ea67 = u2h2(eav.w);
    float a[8] = {(float)ea01.x, (float)ea01.y, (float)ea23.x, (float)ea23.y,
                  (float)ea45.x, (float)ea45.y, (float)ea67.x, 0.f};
    #pragma unroll
    for (int d = 0; d < 8; ++d) {
        float e = el[d];
        #pragma unroll
        for (int kp = 0; kp < 4; ++kp) {
            h2 w = u2h2(Wp[d * 4 + kp]);
            e += a[kp * 2] * (float)w.x + a[kp * 2 + 1] * (float)w.y;
        }
        el[d] = e;
    }
#endif
    acc0.x += fmaxf(__uint_as_float(xv.x << 16)         + el[0], 0.f);
    acc0.y += fmaxf(__uint_as_float(xv.x & 0xffff0000u) + el[1], 0.f);
    acc0.z += fmaxf(__uint_as_float(xv.y << 16)         + el[2], 0.f);
    acc0.w += fmaxf(__uint_as_float(xv.y & 0xffff0000u) + el[3], 0.f);
    acc1.x += fmaxf(__uint_as_float(xv.z << 16)         + el[4], 0.f);
    acc1.y += fmaxf(__uint_as_float(xv.z & 0xffff0000u) + el[5], 0.f);
    acc1.z += fmaxf(__uint_as_float(xv.w << 16)         + el[6], 0.f);
    acc1.w += fmaxf(__uint_as_float(xv.w & 0xffff0000u) + el[7], 0.f);
}

__global__ __launch_bounds__(256, 4)
void aggregate(const float* __restrict__ x, const unsigned short* __restrict__ xb,
               float* __restrict__ h,
               const uint4* __restrict__ ea16,
               const int* __restrict__ srcc,
               const int* __restrict__ row_off,
               const float* __restrict__ eW, const float* __restrict__ eb) {
    int t = threadIdx.x;
    int nl = t >> 4, lane = t & 15, c0 = lane * 8;
    int n = blockIdx.x * NBA + nl;

    unsigned Wp[32];
    #pragma unroll
    for (int d = 0; d < 8; ++d) {
        #pragma unroll
        for (int kp = 0; kp < 4; ++kp) {
            float w0 = eW[(kp * 2) * DIM + c0 + d];
            float w1 = (kp * 2 + 1 < EDIM) ? eW[(kp * 2 + 1) * DIM + c0 + d] : 0.f;
            Wp[d * 4 + kp] = packh2(w0, w1);
        }
    }
    float4 b0 = *reinterpret_cast<const float4*>(eb + c0);
    float4 b1 = *reinterpret_cast<const float4*>(eb + c0 + 4);
    #pragma unroll
    for (int k = 0; k < 32; ++k) asm volatile("" : "+v"(Wp[k]));
    asm volatile("" : "+v"(b0.x), "+v"(b0.y), "+v"(b0.z), "+v"(b0.w));
    asm volatile("" : "+v"(b1.x), "+v"(b1.y), "+v"(b1.z), "+v"(b1.w));

    float4 acc0 = *reinterpret_cast<const float4*>(x + (size_t)n * DIM + c0);
    float4 acc1 = *reinterpret_cast<const float4*>(x + (size_t)n * DIM + c0 + 4);
    int idx = row_off[n], end = row_off[n + 1];

    int s_c[4];
    bool have = (idx + 4 <= end);
    if (have) {
        #pragma unroll
        for (int j = 0; j < 4; ++j) s_c[j] = srcc[idx + j];
    }
    while (have) {
        uint4 ea[4], xv[4];
        #pragma unroll
        for (int j = 0; j < 4; ++j) ea[j] = ea16[idx + j];
        #pragma unroll
        for (int j = 0; j < 4; ++j) xv[j] = *reinterpret_cast<const uint4*>(xb + (size_t)s_c[j] * DIM + c0);
        idx += 4;
        bool nxt = (idx + 4 <= end);
        int s_n[4];
        if (nxt) {
            #pragma unroll
            for (int j = 0; j < 4; ++j) s_n[j] = srcc[idx + j];
        }
        #pragma unroll
        for (int j = 0; j < 4; ++j) edge_accum8(acc0, acc1, ea[j], xv[j], Wp, b0, b1);
        if (nxt) {
            #pragma unroll
            for (int j = 0; j < 4; ++j) s_c[j] = s_n[j];
        }
        have = nxt;
    }
    for (; idx < end; ++idx) {
        int s = srcc[idx];
        uint4 ea = ea16[idx];
        uint4 xv = *reinterpret_cast<const uint4*>(xb + (size_t)s * DIM + c0);
        edge_accum8(acc0, acc1, ea, xv, Wp, b0, b1);
    }
    *reinterpret_cast<float4*>(h + (size_t)n * DIM + c0) = acc0;
    *reinterpret_cast<float4*>(h + (size_t)n * DIM + c0 + 4) = acc1;
}

// ---------------- fused double MFMA GEMM, TM=32: 1564 blocks (~8/CU) ----------------
// x = bn2relu( bn1relu(h@W1+b1) @ W2 + b2 ); persistent B frags (R12-style).

__global__ __launch_bounds__(256)
void gemm2x(const float* __restrict__ in, float* __restrict__ outx,
            unsigned short* __restrict__ xb_out,
            const unsigned short* __restrict__ W1hi, const unsigned short* __restrict__ W1lo,
            const unsigned short* __restrict__ W2hi, const unsigned short* __restrict__ W2lo,
            const float* __restrict__ b1,
            const float* __restrict__ bn1g, const float* __restrict__ bn1b,
            const float* __restrict__ bn1m, const float* __restrict__ bn1v,
            const float* __restrict__ b2,
            const float* __restrict__ bn2g, const float* __restrict__ bn2b,
            const float* __restrict__ bn2m, const float* __restrict__ bn2v) {
    __shared__ __align__(16) unsigned short A2[TM * AST];   // 16896 B
    int t = threadIdx.x;
    int r0 = blockIdx.x * TM;
    int w = t >> 6;
    int lane = t & 63;
    int q = lane >> 4;
    int l16 = lane & 15;

    // B1 register fragments (in flight during A staging)
    bf16x8 bh[2][4], bl[2][4];
    #pragma unroll
    for (int nt = 0; nt < 2; ++nt) {
        int n = w * 32 + nt * 16 + l16;
        const bf16x8* gh = reinterpret_cast<const bf16x8*>(W1hi + (size_t)n * DIM);
        const bf16x8* gl = reinterpret_cast<const bf16x8*>(W1lo + (size_t)n * DIM);
        #pragma unroll
        for (int kc = 0; kc < 4; ++kc) {
            bh[nt][kc] = gh[kc * 4 + q];
            bl[nt][kc] = gl[kc * 4 + q];
        }
    }

    // stage A (hi/lo split): 1024 float4, 4 per thread
    #pragma unroll
    for (int i = 0; i < 4; ++i) {
        int idx = t + i * 256;
        int row = idx >> 5;
        int kp = (idx & 31) * 4;
        float4 v = reinterpret_cast<const float4*>(in + (size_t)r0 * DIM)[idx];
        unsigned short h0 = f2bf(v.x), h1 = f2bf(v.y), h2_ = f2bf(v.z), h3 = f2bf(v.w);
        ushort4 hv; hv.x = h0; hv.y = h1; hv.z = h2_; hv.w = h3;
        ushort4 lv;
        lv.x = f2bf(v.x - bf2f(h0)); lv.y = f2bf(v.y - bf2f(h1));
        lv.z = f2bf(v.z - bf2f(h2_)); lv.w = f2bf(v.w - bf2f(h3));
        *reinterpret_cast<ushort4*>(&A2[row * AST + kp]) = hv;
        *reinterpret_cast<ushort4*>(&A2[row * AST + 128 + kp]) = lv;
    }
    __syncthreads();

    f32x4 acc[2][2];
    #pragma unroll
    for (int mt = 0; mt < 2; ++mt)
        #pragma unroll
        for (int nt = 0; nt < 2; ++nt)
            acc[mt][nt] = (f32x4){0.f, 0.f, 0.f, 0.f};

    #pragma unroll
    for (int kc = 0; kc < 4; ++kc) {
        bf16x8 ahi[2], alo[2];
        #pragma unroll
        for (int mt = 0; mt < 2; ++mt) {
            ahi[mt] = *reinterpret_cast<const bf16x8*>(&A2[(mt * 16 + l16) * AST + kc * 32 + q * 8]);
            alo[mt] = *reinterpret_cast<const bf16x8*>(&A2[(mt * 16 + l16) * AST + 128 + kc * 32 + q * 8]);
        }
        #pragma unroll
        for (int mt = 0; mt < 2; ++mt)
            #pragma unroll
            for (int nt = 0; nt < 2; ++nt) {
                acc[mt][nt] = __builtin_amdgcn_mfma_f32_16x16x32_bf16(ahi[mt], bh[nt][kc], acc[mt][nt], 0, 0, 0);
                acc[mt][nt] = __builtin_amdgcn_mfma_f32_16x16x32_bf16(ahi[mt], bl[nt][kc], acc[mt][nt], 0, 0, 0);
                acc[mt][nt] = __builtin_amdgcn_mfma_f32_16x16x32_bf16(alo[mt], bh[nt][kc], acc[mt][nt], 0, 0, 0);
            }
    }
    __syncthreads();   // all Kloop1 reads done before A2 overwrite

    // B2 fragments issued FIRST: latency hides under epilogue-1 VALU+LDS
    #pragma unroll
    for (int nt = 0; nt < 2; ++nt) {
        int n = w * 32 + nt * 16 + l16;
        const bf16x8* gh = reinterpret_cast<const bf16x8*>(W2hi + (size_t)n * DIM);
        const bf16x8* gl = reinterpret_cast<const bf16x8*>(W2lo + (size_t)n * DIM);
        #pragma unroll
        for (int kc = 0; kc < 4; ++kc) {
            bh[nt][kc] = gh[kc * 4 + q];
            bl[nt][kc] = gl[kc * 4 + q];
        }
    }

    // epilogue 1: bias + BN1 + ReLU -> back into A2 (hi/lo), local rows
    #pragma unroll
    for (int nt = 0; nt < 2; ++nt) {
        int col = w * 32 + nt * 16 + l16;
        float bias = b1[col];
        float sc = bn1g[col] * rsqrtf(bn1v[col] + BN_EPS);
        float sh = bn1b[col] - bn1m[col] * sc;
        #pragma unroll
        for (int mt = 0; mt < 2; ++mt) {
            #pragma unroll
            for (int r = 0; r < 4; ++r) {
                int rowl = mt * 16 + q * 4 + r;
                float o = fmaxf((acc[mt][nt][r] + bias) * sc + sh, 0.f);
                unsigned short hi = f2bf(o);
                A2[rowl * AST + col] = hi;
                A2[rowl * AST + 128 + col] = f2bf(o - bf2f(hi));
            }
        }
    }
    __syncthreads();

    #pragma unroll
    for (int mt = 0; mt < 2; ++mt)
        #pragma unroll
        for (int nt = 0; nt < 2; ++nt)
            acc[mt][nt] = (f32x4){0.f, 0.f, 0.f, 0.f};

    #pragma unroll
    for (int kc = 0; kc < 4; ++kc) {
        bf16x8 ahi[2], alo[2];
        #pragma unroll
        for (int mt = 0; mt < 2; ++mt) {
            ahi[mt] = *reinterpret_cast<const bf16x8*>(&A2[(mt * 16 + l16) * AST + kc * 32 + q * 8]);
            alo[mt] = *reinterpret_cast<const bf16x8*>(&A2[(mt * 16 + l16) * AST + 128 + kc * 32 + q * 8]);
        }
        #pragma unroll
        for (int mt = 0; mt < 2; ++mt)
            #pragma unroll
            for (int nt = 0; nt < 2; ++nt) {
                acc[mt][nt] = __builtin_amdgcn_mfma_f32_16x16x32_bf16(ahi[mt], bh[nt][kc], acc[mt][nt], 0, 0, 0);
                acc[mt][nt] = __builtin_amdgcn_mfma_f32_16x16x32_bf16(ahi[mt], bl[nt][kc], acc[mt][nt], 0, 0, 0);
                acc[mt][nt] = __builtin_amdgcn_mfma_f32_16x16x32_bf16(alo[mt], bh[nt][kc], acc[mt][nt], 0, 0, 0);
            }
    }

    // epilogue 2: bias + BN2 + ReLU -> x + xb
    #pragma unroll
    for (int nt = 0; nt < 2; ++nt) {
        int col = w * 32 + nt * 16 + l16;
        float bias = b2[col];
        float sc = bn2g[col] * rsqrtf(bn2v[col] + BN_EPS);
        float sh = bn2b[col] - bn2m[col] * sc;
        #pragma unroll
        for (int mt = 0; mt < 2; ++mt) {
            #pragma unroll
            for (int r = 0; r < 4; ++r) {
                int row = r0 + mt * 16 + q * 4 + r;
                float o = fmaxf((acc[mt][nt][r] + bias) * sc + sh, 0.f);
                outx[(size_t)row * DIM + col] = o;
                xb_out[(size_t)row * DIM + col] = f2bf(o);
            }
        }
    }
}

// ---------------- global mean pool (batch sorted) ----------------

__global__ __launch_bounds__(256)
void pool_kernel(const float* __restrict__ x, const int* __restrict__ batch,
                 float* __restrict__ g) {
    __shared__ float sh[256];
    __shared__ int sb[2];
    int gid = blockIdx.x;
    int t = threadIdx.x;
    if (t < 2) {
        int tgt = gid + t;
        int lo = 0, hi = N_NODES;
        while (lo < hi) { int mid = (lo + hi) >> 1; if (batch[mid] < tgt) lo = mid + 1; else hi = mid; }
        sb[t] = lo;
    }
    __syncthreads();
    int lo = sb[0], hi = sb[1];
    int d = t & 127, half = t >> 7;
    float a = 0.f;
    for (int n = lo + half; n < hi; n += 2) a += x[(size_t)n * DIM + d];
    sh[t] = a;
    __syncthreads();
    if (t < DIM) {
        float cnt = fmaxf((float)(hi - lo), 1.f);
        g[gid * DIM + t] = (sh[t] + sh[t + 128]) / cnt;
    }
}

// ---------------- head ----------------

__global__ __launch_bounds__(128)
void head1_kernel(const float* __restrict__ g, const float* __restrict__ W1,
                  const float* __restrict__ b1, float* __restrict__ h1) {
    __shared__ float gs[DIM];
    int gid = blockIdx.x, c = threadIdx.x;
    gs[c] = g[gid * DIM + c];
    __syncthreads();
    float acc = b1[c];
    for (int k = 0; k < DIM; ++k) acc += gs[k] * W1[k * DIM + c];
    h1[gid * DIM + c] = fmaxf(acc, 0.f);
}

__global__ __launch_bounds__(64)
void head2_kernel(const float* __restrict__ h1, const float* __restrict__ W2,
                  const float* __restrict__ b2, float* __restrict__ out) {
    __shared__ float hs[DIM];
    int gid = blockIdx.x;
    int t = threadIdx.x;
    hs[t] = h1[gid * DIM + t];
    hs[t + 64] = h1[gid * DIM + t + 64];
    __syncthreads();
    if (t < NCLASS) {
        float acc = b2[t];
        for (int k = 0; k < DIM; ++k) acc += hs[k] * W2[k * NCLASS + t];
        out[gid * NCLASS + t] = acc;
    }
}

// ---------------- launch ----------------

extern "C" void kernel_launch(void* const* d_in, const int* in_sizes, int n_in,
                              void* d_out, int out_size, void* d_ws, size_t ws_size,
                              hipStream_t stream) {
    const float* edge_attr = (const float*)d_in[0];
    const int*   edge_index = (const int*)d_in[1];
    const int*   batch = (const int*)d_in[2];
    const float* node_emb = (const float*)d_in[3];
    const float* edge_W = (const float*)d_in[4];
    const float* edge_b = (const float*)d_in[5];
    const float* mlp_W1 = (const float*)d_in[6];
    const float* mlp_b1 = (const float*)d_in[7];
    const float* bn1_g = (const float*)d_in[8];
    const float* bn1_b = (const float*)d_in[9];
    const float* bn1_m = (const float*)d_in[10];
    const float* bn1_v = (const float*)d_in[11];
    const float* mlp_W2 = (const float*)d_in[12];
    const float* mlp_b2 = (const float*)d_in[13];
    const float* bn2_g = (const float*)d_in[14];
    const float* bn2_b = (const float*)d_in[15];
    const float* bn2_m = (const float*)d_in[16];
    const float* bn2_v = (const float*)d_in[17];
    const float* head_W1 = (const float*)d_in[18];
    const float* head_b1 = (const float*)d_in[19];
    const float* head_W2 = (const float*)d_in[20];
    const float* head_b2 = (const float*)d_in[21];
    float* out = (float*)d_out;

    const int* src = edge_index;
    const int* dst = edge_index + N_EDGES;

    size_t off = 0;
    auto carve = [&](size_t bytes) {
        void* p = (char*)d_ws + off;
        off += (bytes + 255) & ~(size_t)255;
        return p;
    };
    float* x            = (float*)carve((size_t)N_PAD * DIM * 4);
    unsigned short* xb  = (unsigned short*)carve((size_t)N_PAD * DIM * 2);
    float* h            = (float*)carve((size_t)N_PAD * DIM * 4);
    uint4* ea16         = (uint4*)carve((size_t)N_EDGES * 16);
    int* srcc           = (int*)carve((size_t)N_EDGES * 4);
    unsigned short* Wthi = (unsigned short*)carve((size_t)2 * LAYERS * DIM * DIM * 2);
    unsigned short* Wtlo = (unsigned short*)carve((size_t)2 * LAYERS * DIM * DIM * 2);
    int* deg      = (int*)carve((size_t)N_NODES * 4);
    int* row_off  = (int*)carve((size_t)(N_NODES + 1) * 4);
    int* cursor   = (int*)carve((size_t)N_NODES * 4);
    int* bsums    = (int*)carve((size_t)NSB * 4);
    float* gbuf   = (float*)carve((size_t)N_GRAPHS * DIM * 4);
    float* h1buf  = (float*)carve((size_t)N_GRAPHS * DIM * 4);
    (void)ws_size;

    // CSR build + single-pass edge scatter
    zero_ints<<<(N_NODES + 255) / 256, 256, 0, stream>>>(deg, N_NODES);
    hist_kernel<<<(N_EDGES + 255) / 256, 256, 0, stream>>>(dst, deg);
    scan1<<<NSB, 256, 0, stream>>>(deg, row_off, bsums);
    scan2<<<1, 256, 0, stream>>>(bsums);
    scan3<<<NSB, 256, 0, stream>>>(row_off, bsums, cursor);
    fill_rec<<<(N_EDGES + 255) / 256, 256, 0, stream>>>(dst, src, edge_attr, cursor, ea16, srcc);

    init_x<<<(N_NODES * DIM + 255) / 256, 256, 0, stream>>>(x, xb, node_emb);
    prep_w<<<(2 * LAYERS * DIM * DIM + 255) / 256, 256, 0, stream>>>(mlp_W1, mlp_W2, Wthi, Wtlo);

    const int gemm_blocks = N_PAD / TM;   // 1564
    for (int l = 0; l < LAYERS; ++l) {
        aggregate<<<N_NODES / NBA, 256, 0, stream>>>(
            x, xb, h, ea16, srcc, row_off,
            edge_W + (size_t)l * EDIM * DIM, edge_b + (size_t)l * DIM);
        gemm2x<<<gemm_blocks, 256, 0, stream>>>(
            h, x, xb,
            Wthi + ((size_t)l << 14), Wtlo + ((size_t)l << 14),
            Wthi + ((size_t)(LAYERS + l) << 14), Wtlo + ((size_t)(LAYERS + l) << 14),
            mlp_b1 + (size_t)l * DIM,
            bn1_g + (size_t)l * DIM, bn1_b + (size_t)l * DIM,
            bn1_m + (size_t)l * DIM, bn1_v + (size_t)l * DIM,
            mlp_b2 + (size_t)l * DIM,
            bn2_g + (size_t)l * DIM, bn2_b + (size_t)l * DIM,
            bn2_m + (size_t)l * DIM, bn2_v + (size_t)l * DIM);
    }

    pool_kernel<<<N_GRAPHS, 256, 0, stream>>>(x, batch, gbuf);
    head1_kernel<<<N_GRAPHS, 128, 0, stream>>>(gbuf, head_W1, head_b1, h1buf);
    head2_kernel<<<N_GRAPHS, 64, 0, stream>>>(h1buf, head_W2, head_b2, out);
}

// Round 15
// 639.437 us; speedup vs baseline: 1.0254x; 1.0254x over previous
//
#include <hip/hip_runtime.h>

#define N_NODES 50000
#define N_PAD   50048   // multiple of 64; pad rows garbage, never consumed
#define N_EDGES 800000
#define N_GRAPHS 500
#define DIM 128
#define EDIM 7
#define LAYERS 5
#define NCLASS 10
#define BN_EPS 1e-5f
#define TM 64           // GEMM tile rows (R12 measured-best config)
#define AST 264         // LDS A row stride (ushort): 528 B = odd 16B multiple -> conflict-free b128
#define NSB ((N_NODES + 256) / 256)   // 196 scan blocks

typedef __attribute__((ext_vector_type(8))) short bf16x8;
typedef __attribute__((ext_vector_type(4))) float f32x4;
typedef _Float16 h2 __attribute__((ext_vector_type(2)));

struct __align__(32) ERec { uint4 ea; int src; int pad0, pad1, pad2; };

__device__ __forceinline__ unsigned short f2bf(float f) {
    unsigned u = __float_as_uint(f);
    u = u + 0x7fffu + ((u >> 16) & 1u);   // RNE
    return (unsigned short)(u >> 16);
}
__device__ __forceinline__ float bf2f(unsigned short h) {
    return __uint_as_float(((unsigned)h) << 16);
}
__device__ __forceinline__ h2 u2h2(unsigned u) {
    union { unsigned u; h2 h; } c; c.u = u; return c.h;
}
__device__ __forceinline__ unsigned h22u(h2 h) {
    union { h2 h; unsigned u; } c; c.h = h; return c.u;
}
__device__ __forceinline__ unsigned packh2(float a, float b) {
    h2 h; h.x = (_Float16)a; h.y = (_Float16)b;   // RNE casts
    return h22u(h);
}

// ---------------- CSR build ----------------

__global__ void zero_ints(int* __restrict__ p, int n) {
    int i = blockIdx.x * 256 + threadIdx.x;
    if (i < n) p[i] = 0;
}

__global__ void hist_kernel(const int* __restrict__ dst, int* __restrict__ deg) {
    int e = blockIdx.x * 256 + threadIdx.x;
    if (e < N_EDGES) atomicAdd(&deg[dst[e]], 1);
}

__global__ __launch_bounds__(256)
void scan1(const int* __restrict__ deg, int* __restrict__ ro, int* __restrict__ bsums) {
    __shared__ int ws[4];
    int t = threadIdx.x;
    int i = blockIdx.x * 256 + t;
    int v = (i < N_NODES) ? deg[i] : 0;
    int lane = t & 63, wv = t >> 6;
    int s = v;
    #pragma unroll
    for (int off = 1; off < 64; off <<= 1) {
        int u = __shfl_up(s, off, 64);
        if (lane >= off) s += u;
    }
    if (lane == 63) ws[wv] = s;
    __syncthreads();
    if (t == 0) {
        int a = 0;
        #pragma unroll
        for (int k = 0; k < 4; ++k) { int x = ws[k]; ws[k] = a; a += x; }
        bsums[blockIdx.x] = a;
    }
    __syncthreads();
    int excl = s - v + ws[wv];
    if (i <= N_NODES) ro[i] = excl;
}

__global__ __launch_bounds__(256)
void scan2(int* __restrict__ bsums) {
    __shared__ int ws[4];
    int t = threadIdx.x;
    int v = (t < NSB) ? bsums[t] : 0;
    int lane = t & 63, wv = t >> 6;
    int s = v;
    #pragma unroll
    for (int off = 1; off < 64; off <<= 1) {
        int u = __shfl_up(s, off, 64);
        if (lane >= off) s += u;
    }
    if (lane == 63) ws[wv] = s;
    __syncthreads();
    if (t == 0) {
        int a = 0;
        #pragma unroll
        for (int k = 0; k < 4; ++k) { int x = ws[k]; ws[k] = a; a += x; }
    }
    __syncthreads();
    if (t < NSB) bsums[t] = s - v + ws[wv];
}

__global__ __launch_bounds__(256)
void scan3(int* __restrict__ ro, const int* __restrict__ bsums, int* __restrict__ cursor) {
    int i = blockIdx.x * 256 + threadIdx.x;
    if (i <= N_NODES) {
        int r = ro[i] + bsums[i >> 8];
        ro[i] = r;
        if (i < N_NODES) cursor[i] = r;
    }
}

// single pass: sequential read of src/dst/edge_attr -> fp16, ONE scattered 32B
// record per edge (combined: 1 dirty line/edge; split arrays measured worse, R14)
__global__ void fill_rec(const int* __restrict__ dst, const int* __restrict__ src,
                         const float* __restrict__ edge_attr,
                         int* __restrict__ cursor, ERec* __restrict__ rec) {
    int e = blockIdx.x * 256 + threadIdx.x;
    if (e < N_EDGES) {
        const float* ap = edge_attr + (size_t)e * EDIM;
        uint4 ea;
        ea.x = packh2(ap[0], ap[1]);
        ea.y = packh2(ap[2], ap[3]);
        ea.z = packh2(ap[4], ap[5]);
        ea.w = packh2(ap[6], 0.f);
        int s = src[e];
        int pos = atomicAdd(&cursor[dst[e]], 1);
        rec[pos].ea = ea;
        rec[pos].src = s;
    }
}

// ---------------- one-time preps ----------------

__global__ void init_x(float* __restrict__ x, unsigned short* __restrict__ xb,
                       const float* __restrict__ emb) {
    int i = blockIdx.x * 256 + threadIdx.x;
    if (i < N_NODES * DIM) {
        float v = emb[i & (DIM - 1)];
        x[i] = v;
        xb[i] = f2bf(v);
    }
}

// W [k][n] fp32 -> transposed hi/lo bf16 Wt[m][n][k]
__global__ void prep_w(const float* __restrict__ W1, const float* __restrict__ W2,
                       unsigned short* __restrict__ Wthi, unsigned short* __restrict__ Wtlo) {
    int i = blockIdx.x * 256 + threadIdx.x;
    if (i >= 2 * LAYERS * DIM * DIM) return;
    int m = i >> 14;
    int n = i & 127;
    int k = (i >> 7) & 127;
    const float* W = (m < LAYERS) ? (W1 + (size_t)m * DIM * DIM)
                                  : (W2 + (size_t)(m - LAYERS) * DIM * DIM);
    float v = W[k * DIM + n];
    unsigned short hi = f2bf(v);
    float lo = v - bf2f(hi);
    size_t o = ((size_t)m << 14) + (size_t)n * DIM + k;
    Wthi[o] = hi;
    Wtlo[o] = f2bf(lo);
}

// ---------------- aggregation: ONE WAVE PER NODE ----------------
// rec[idx]/row_off[n] are wave-uniform -> scalar loads (SALU runs the loop in
// parallel with VALU); ea enters fdot2 as the SGPR operand; xb gather is one
// coalesced 4B/lane load (256B row). Lane owns 2 features.

#if __has_builtin(__builtin_amdgcn_fdot2)
#define HAVE_FDOT2 1
#else
#define HAVE_FDOT2 0
#endif

__device__ __forceinline__ void edge_accum2(float& acc0, float& acc1,
                                            uint4 eav, unsigned xv,
                                            const unsigned* Wp0, const unsigned* Wp1,
                                            float b0, float b1) {
    float e0 = b0, e1 = b1;
#if HAVE_FDOT2
    e0 = __builtin_amdgcn_fdot2(u2h2(eav.x), u2h2(Wp0[0]), e0, false);
    e0 = __builtin_amdgcn_fdot2(u2h2(eav.y), u2h2(Wp0[1]), e0, false);
    e0 = __builtin_amdgcn_fdot2(u2h2(eav.z), u2h2(Wp0[2]), e0, false);
    e0 = __builtin_amdgcn_fdot2(u2h2(eav.w), u2h2(Wp0[3]), e0, false);
    e1 = __builtin_amdgcn_fdot2(u2h2(eav.x), u2h2(Wp1[0]), e1, false);
    e1 = __builtin_amdgcn_fdot2(u2h2(eav.y), u2h2(Wp1[1]), e1, false);
    e1 = __builtin_amdgcn_fdot2(u2h2(eav.z), u2h2(Wp1[2]), e1, false);
    e1 = __builtin_amdgcn_fdot2(u2h2(eav.w), u2h2(Wp1[3]), e1, false);
#else
    h2 ea01 = u2h2(eav.x), ea23 = u2h2(eav.y), ea45 = u2h2(eav.z), ea67 = u2h2(eav.w);
    float a[8] = {(float)ea01.x, (float)ea01.y, (float)ea23.x, (float)ea23.y,
                  (float)ea45.x, (float)ea45.y, (float)ea67.x, 0.f};
    #pragma unroll
    for (int kp = 0; kp < 4; ++kp) {
        h2 w0 = u2h2(Wp0[kp]), w1 = u2h2(Wp1[kp]);
        e0 += a[kp * 2] * (float)w0.x + a[kp * 2 + 1] * (float)w0.y;
        e1 += a[kp * 2] * (float)w1.x + a[kp * 2 + 1] * (float)w1.y;
    }
#endif
    acc0 += fmaxf(__uint_as_float(xv << 16)         + e0, 0.f);
    acc1 += fmaxf(__uint_as_float(xv & 0xffff0000u) + e1, 0.f);
}

__global__ __launch_bounds__(256, 8)
void aggregate(const float* __restrict__ x, const unsigned short* __restrict__ xb,
               float* __restrict__ h,
               const ERec* __restrict__ rec,
               const int* __restrict__ row_off,
               const float* __restrict__ eW, const float* __restrict__ eb) {
    int t = threadIdx.x;
    int wv = __builtin_amdgcn_readfirstlane(t >> 6);  // wave id in block (uniform)
    int lane = t & 63;
    int c0 = lane * 2;
    int n = blockIdx.x * 4 + wv;                      // node for this wave (uniform)

    // Wp{0,1}[kp] = (W[2kp][c0+d], W[2kp+1][c0+d]) fp16 pairs; k=7 padded 0
    unsigned Wp0[4], Wp1[4];
    #pragma unroll
    for (int kp = 0; kp < 4; ++kp) {
        float w00 = eW[(kp * 2) * DIM + c0];
        float w01 = (kp * 2 + 1 < EDIM) ? eW[(kp * 2 + 1) * DIM + c0] : 0.f;
        float w10 = eW[(kp * 2) * DIM + c0 + 1];
        float w11 = (kp * 2 + 1 < EDIM) ? eW[(kp * 2 + 1) * DIM + c0 + 1] : 0.f;
        Wp0[kp] = packh2(w00, w01);
        Wp1[kp] = packh2(w10, w11);
    }
    float b0 = eb[c0], b1 = eb[c0 + 1];
    #pragma unroll
    for (int k = 0; k < 4; ++k) asm volatile("" : "+v"(Wp0[k]), "+v"(Wp1[k]));
    asm volatile("" : "+v"(b0), "+v"(b1));

    float acc0 = x[(size_t)n * DIM + c0];
    float acc1 = x[(size_t)n * DIM + c0 + 1];
    int idx = row_off[n], end = row_off[n + 1];       // uniform -> s_load

    // 2-edge unroll: two xv loads in flight per iteration
    for (; idx + 2 <= end; idx += 2) {
        ERec r0 = rec[idx];                           // uniform -> s_load
        ERec r1 = rec[idx + 1];
        unsigned xv0 = *reinterpret_cast<const unsigned*>(xb + (size_t)r0.src * DIM + c0);
        unsigned xv1 = *reinterpret_cast<const unsigned*>(xb + (size_t)r1.src * DIM + c0);
        edge_accum2(acc0, acc1, r0.ea, xv0, Wp0, Wp1, b0, b1);
        edge_accum2(acc0, acc1, r1.ea, xv1, Wp0, Wp1, b0, b1);
    }
    if (idx < end) {
        ERec r0 = rec[idx];
        unsigned xv0 = *reinterpret_cast<const unsigned*>(xb + (size_t)r0.src * DIM + c0);
        edge_accum2(acc0, acc1, r0.ea, xv0, Wp0, Wp1, b0, b1);
    }

    float2 o; o.x = acc0; o.y = acc1;
    *reinterpret_cast<float2*>(h + (size_t)n * DIM + c0) = o;
}

// ---------------- fused double MFMA GEMM (R12 measured-best: TM=64, persistent B) ----------------

__global__ __launch_bounds__(256)
void gemm2x(const float* __restrict__ in, float* __restrict__ outx,
            unsigned short* __restrict__ xb_out,
            const unsigned short* __restrict__ W1hi, const unsigned short* __restrict__ W1lo,
            const unsigned short* __restrict__ W2hi, const unsigned short* __restrict__ W2lo,
            const float* __restrict__ b1,
            const float* __restrict__ bn1g, const float* __restrict__ bn1b,
            const float* __restrict__ bn1m, const float* __restrict__ bn1v,
            const float* __restrict__ b2,
            const float* __restrict__ bn2g, const float* __restrict__ bn2b,
            const float* __restrict__ bn2m, const float* __restrict__ bn2v) {
    __shared__ __align__(16) unsigned short A2[TM * AST];   // 33792 B
    int t = threadIdx.x;
    int r0 = blockIdx.x * TM;
    int w = t >> 6;
    int lane = t & 63;
    int q = lane >> 4;
    int l16 = lane & 15;

    // B1 register fragments (in flight during A staging)
    bf16x8 bh[2][4], bl[2][4];
    #pragma unroll
    for (int nt = 0; nt < 2; ++nt) {
        int n = w * 32 + nt * 16 + l16;
        const bf16x8* gh = reinterpret_cast<const bf16x8*>(W1hi + (size_t)n * DIM);
        const bf16x8* gl = reinterpret_cast<const bf16x8*>(W1lo + (size_t)n * DIM);
        #pragma unroll
        for (int kc = 0; kc < 4; ++kc) {
            bh[nt][kc] = gh[kc * 4 + q];
            bl[nt][kc] = gl[kc * 4 + q];
        }
    }

    // stage A (hi/lo split)
    #pragma unroll
    for (int i = 0; i < 8; ++i) {
        int idx = t + i * 256;
        int row = idx >> 5;
        int kp = (idx & 31) * 4;
        float4 v = reinterpret_cast<const float4*>(in + (size_t)r0 * DIM)[idx];
        unsigned short h0 = f2bf(v.x), h1 = f2bf(v.y), h2_ = f2bf(v.z), h3 = f2bf(v.w);
        ushort4 hv; hv.x = h0; hv.y = h1; hv.z = h2_; hv.w = h3;
        ushort4 lv;
        lv.x = f2bf(v.x - bf2f(h0)); lv.y = f2bf(v.y - bf2f(h1));
        lv.z = f2bf(v.z - bf2f(h2_)); lv.w = f2bf(v.w - bf2f(h3));
        *reinterpret_cast<ushort4*>(&A2[row * AST + kp]) = hv;
        *reinterpret_cast<ushort4*>(&A2[row * AST + 128 + kp]) = lv;
    }
    __syncthreads();

    f32x4 acc[4][2];
    #pragma unroll
    for (int mt = 0; mt < 4; ++mt)
        #pragma unroll
        for (int nt = 0; nt < 2; ++nt)
            acc[mt][nt] = (f32x4){0.f, 0.f, 0.f, 0.f};

    #pragma unroll
    for (int kc = 0; kc < 4; ++kc) {
        bf16x8 ahi[4], alo[4];
        #pragma unroll
        for (int mt = 0; mt < 4; ++mt) {
            ahi[mt] = *reinterpret_cast<const bf16x8*>(&A2[(mt * 16 + l16) * AST + kc * 32 + q * 8]);
            alo[mt] = *reinterpret_cast<const bf16x8*>(&A2[(mt * 16 + l16) * AST + 128 + kc * 32 + q * 8]);
        }
        #pragma unroll
        for (int mt = 0; mt < 4; ++mt)
            #pragma unroll
            for (int nt = 0; nt < 2; ++nt) {
                acc[mt][nt] = __builtin_amdgcn_mfma_f32_16x16x32_bf16(ahi[mt], bh[nt][kc], acc[mt][nt], 0, 0, 0);
                acc[mt][nt] = __builtin_amdgcn_mfma_f32_16x16x32_bf16(ahi[mt], bl[nt][kc], acc[mt][nt], 0, 0, 0);
                acc[mt][nt] = __builtin_amdgcn_mfma_f32_16x16x32_bf16(alo[mt], bh[nt][kc], acc[mt][nt], 0, 0, 0);
            }
    }
    __syncthreads();   // all Kloop1 reads done before A2 overwrite

    // B2 fragments issued FIRST: latency hides under epilogue-1 VALU+LDS
    #pragma unroll
    for (int nt = 0; nt < 2; ++nt) {
        int n = w * 32 + nt * 16 + l16;
        const bf16x8* gh = reinterpret_cast<const bf16x8*>(W2hi + (size_t)n * DIM);
        const bf16x8* gl = reinterpret_cast<const bf16x8*>(W2lo + (size_t)n * DIM);
        #pragma unroll
        for (int kc = 0; kc < 4; ++kc) {
            bh[nt][kc] = gh[kc * 4 + q];
            bl[nt][kc] = gl[kc * 4 + q];
        }
    }

    // epilogue 1: bias + BN1 + ReLU -> back into A2 (hi/lo), local rows
    #pragma unroll
    for (int nt = 0; nt < 2; ++nt) {
        int col = w * 32 + nt * 16 + l16;
        float bias = b1[col];
        float sc = bn1g[col] * rsqrtf(bn1v[col] + BN_EPS);
        float sh = bn1b[col] - bn1m[col] * sc;
        #pragma unroll
        for (int mt = 0; mt < 4; ++mt) {
            #pragma unroll
            for (int r = 0; r < 4; ++r) {
                int rowl = mt * 16 + q * 4 + r;
                float o = fmaxf((acc[mt][nt][r] + bias) * sc + sh, 0.f);
                unsigned short hi = f2bf(o);
                A2[rowl * AST + col] = hi;
                A2[rowl * AST + 128 + col] = f2bf(o - bf2f(hi));
            }
        }
    }
    __syncthreads();

    #pragma unroll
    for (int mt = 0; mt < 4; ++mt)
        #pragma unroll
        for (int nt = 0; nt < 2; ++nt)
            acc[mt][nt] = (f32x4){0.f, 0.f, 0.f, 0.f};

    #pragma unroll
    for (int kc = 0; kc < 4; ++kc) {
        bf16x8 ahi[4], alo[4];
        #pragma unroll
        for (int mt = 0; mt < 4; ++mt) {
            ahi[mt] = *reinterpret_cast<const bf16x8*>(&A2[(mt * 16 + l16) * AST + kc * 32 + q * 8]);
            alo[mt] = *reinterpret_cast<const bf16x8*>(&A2[(mt * 16 + l16) * AST + 128 + kc * 32 + q * 8]);
        }
        #pragma unroll
        for (int mt = 0; mt < 4; ++mt)
            #pragma unroll
            for (int nt = 0; nt < 2; ++nt) {
                acc[mt][nt] = __builtin_amdgcn_mfma_f32_16x16x32_bf16(ahi[mt], bh[nt][kc], acc[mt][nt], 0, 0, 0);
                acc[mt][nt] = __builtin_amdgcn_mfma_f32_16x16x32_bf16(ahi[mt], bl[nt][kc], acc[mt][nt], 0, 0, 0);
                acc[mt][nt] = __builtin_amdgcn_mfma_f32_16x16x32_bf16(alo[mt], bh[nt][kc], acc[mt][nt], 0, 0, 0);
            }
    }

    // epilogue 2: bias + BN2 + ReLU -> x + xb
    #pragma unroll
    for (int nt = 0; nt < 2; ++nt) {
        int col = w * 32 + nt * 16 + l16;
        float bias = b2[col];
        float sc = bn2g[col] * rsqrtf(bn2v[col] + BN_EPS);
        float sh = bn2b[col] - bn2m[col] * sc;
        #pragma unroll
        for (int mt = 0; mt < 4; ++mt) {
            #pragma unroll
            for (int r = 0; r < 4; ++r) {
                int row = r0 + mt * 16 + q * 4 + r;
                float o = fmaxf((acc[mt][nt][r] + bias) * sc + sh, 0.f);
                outx[(size_t)row * DIM + col] = o;
                xb_out[(size_t)row * DIM + col] = f2bf(o);
            }
        }
    }
}

// ---------------- global mean pool (batch sorted) ----------------

__global__ __launch_bounds__(256)
void pool_kernel(const float* __restrict__ x, const int* __restrict__ batch,
                 float* __restrict__ g) {
    __shared__ float sh[256];
    __shared__ int sb[2];
    int gid = blockIdx.x;
    int t = threadIdx.x;
    if (t < 2) {
        int tgt = gid + t;
        int lo = 0, hi = N_NODES;
        while (lo < hi) { int mid = (lo + hi) >> 1; if (batch[mid] < tgt) lo = mid + 1; else hi = mid; }
        sb[t] = lo;
    }
    __syncthreads();
    int lo = sb[0], hi = sb[1];
    int d = t & 127, half = t >> 7;
    float a = 0.f;
    for (int n = lo + half; n < hi; n += 2) a += x[(size_t)n * DIM + d];
    sh[t] = a;
    __syncthreads();
    if (t < DIM) {
        float cnt = fmaxf((float)(hi - lo), 1.f);
        g[gid * DIM + t] = (sh[t] + sh[t + 128]) / cnt;
    }
}

// ---------------- head ----------------

__global__ __launch_bounds__(128)
void head1_kernel(const float* __restrict__ g, const float* __restrict__ W1,
                  const float* __restrict__ b1, float* __restrict__ h1) {
    __shared__ float gs[DIM];
    int gid = blockIdx.x, c = threadIdx.x;
    gs[c] = g[gid * DIM + c];
    __syncthreads();
    float acc = b1[c];
    for (int k = 0; k < DIM; ++k) acc += gs[k] * W1[k * DIM + c];
    h1[gid * DIM + c] = fmaxf(acc, 0.f);
}

__global__ __launch_bounds__(64)
void head2_kernel(const float* __restrict__ h1, const float* __restrict__ W2,
                  const float* __restrict__ b2, float* __restrict__ out) {
    __shared__ float hs[DIM];
    int gid = blockIdx.x;
    int t = threadIdx.x;
    hs[t] = h1[gid * DIM + t];
    hs[t + 64] = h1[gid * DIM + t + 64];
    __syncthreads();
    if (t < NCLASS) {
        float acc = b2[t];
        for (int k = 0; k < DIM; ++k) acc += hs[k] * W2[k * NCLASS + t];
        out[gid * NCLASS + t] = acc;
    }
}

// ---------------- launch ----------------

extern "C" void kernel_launch(void* const* d_in, const int* in_sizes, int n_in,
                              void* d_out, int out_size, void* d_ws, size_t ws_size,
                              hipStream_t stream) {
    const float* edge_attr = (const float*)d_in[0];
    const int*   edge_index = (const int*)d_in[1];
    const int*   batch = (const int*)d_in[2];
    const float* node_emb = (const float*)d_in[3];
    const float* edge_W = (const float*)d_in[4];
    const float* edge_b = (const float*)d_in[5];
    const float* mlp_W1 = (const float*)d_in[6];
    const float* mlp_b1 = (const float*)d_in[7];
    const float* bn1_g = (const float*)d_in[8];
    const float* bn1_b = (const float*)d_in[9];
    const float* bn1_m = (const float*)d_in[10];
    const float* bn1_v = (const float*)d_in[11];
    const float* mlp_W2 = (const float*)d_in[12];
    const float* mlp_b2 = (const float*)d_in[13];
    const float* bn2_g = (const float*)d_in[14];
    const float* bn2_b = (const float*)d_in[15];
    const float* bn2_m = (const float*)d_in[16];
    const float* bn2_v = (const float*)d_in[17];
    const float* head_W1 = (const float*)d_in[18];
    const float* head_b1 = (const float*)d_in[19];
    const float* head_W2 = (const float*)d_in[20];
    const float* head_b2 = (const float*)d_in[21];
    float* out = (float*)d_out;

    const int* src = edge_index;
    const int* dst = edge_index + N_EDGES;

    size_t off = 0;
    auto carve = [&](size_t bytes) {
        void* p = (char*)d_ws + off;
        off += (bytes + 255) & ~(size_t)255;
        return p;
    };
    float* x            = (float*)carve((size_t)N_PAD * DIM * 4);
    unsigned short* xb  = (unsigned short*)carve((size_t)N_PAD * DIM * 2);
    float* h            = (float*)carve((size_t)N_PAD * DIM * 4);
    ERec* rec           = (ERec*)carve((size_t)N_EDGES * sizeof(ERec));
    unsigned short* Wthi = (unsigned short*)carve((size_t)2 * LAYERS * DIM * DIM * 2);
    unsigned short* Wtlo = (unsigned short*)carve((size_t)2 * LAYERS * DIM * DIM * 2);
    int* deg      = (int*)carve((size_t)N_NODES * 4);
    int* row_off  = (int*)carve((size_t)(N_NODES + 1) * 4);
    int* cursor   = (int*)carve((size_t)N_NODES * 4);
    int* bsums    = (int*)carve((size_t)NSB * 4);
    float* gbuf   = (float*)carve((size_t)N_GRAPHS * DIM * 4);
    float* h1buf  = (float*)carve((size_t)N_GRAPHS * DIM * 4);
    (void)ws_size;

    // CSR build + single-pass edge scatter
    zero_ints<<<(N_NODES + 255) / 256, 256, 0, stream>>>(deg, N_NODES);
    hist_kernel<<<(N_EDGES + 255) / 256, 256, 0, stream>>>(dst, deg);
    scan1<<<NSB, 256, 0, stream>>>(deg, row_off, bsums);
    scan2<<<1, 256, 0, stream>>>(bsums);
    scan3<<<NSB, 256, 0, stream>>>(row_off, bsums, cursor);
    fill_rec<<<(N_EDGES + 255) / 256, 256, 0, stream>>>(dst, src, edge_attr, cursor, rec);

    init_x<<<(N_NODES * DIM + 255) / 256, 256, 0, stream>>>(x, xb, node_emb);
    prep_w<<<(2 * LAYERS * DIM * DIM + 255) / 256, 256, 0, stream>>>(mlp_W1, mlp_W2, Wthi, Wtlo);

    const int gemm_blocks = N_PAD / TM;   // 782
    for (int l = 0; l < LAYERS; ++l) {
        aggregate<<<N_NODES / 4, 256, 0, stream>>>(
            x, xb, h, rec, row_off,
            edge_W + (size_t)l * EDIM * DIM, edge_b + (size_t)l * DIM);
        gemm2x<<<gemm_blocks, 256, 0, stream>>>(
            h, x, xb,
            Wthi + ((size_t)l << 14), Wtlo + ((size_t)l << 14),
            Wthi + ((size_t)(LAYERS + l) << 14), Wtlo + ((size_t)(LAYERS + l) << 14),
            mlp_b1 + (size_t)l * DIM,
            bn1_g + (size_t)l * DIM, bn1_b + (size_t)l * DIM,
            bn1_m + (size_t)l * DIM, bn1_v + (size_t)l * DIM,
            mlp_b2 + (size_t)l * DIM,
            bn2_g + (size_t)l * DIM, bn2_b + (size_t)l * DIM,
            bn2_m + (size_t)l * DIM, bn2_v + (size_t)l * DIM);
    }

    pool_kernel<<<N_GRAPHS, 256, 0, stream>>>(x, batch, gbuf);
    head1_kernel<<<N_GRAPHS, 128, 0, stream>>>(gbuf, head_W1, head_b1, h1buf);
    head2_kernel<<<N_GRAPHS, 64, 0, stream>>>(h1buf, head_W2, head_b2, out);
}

// Round 16
// 622.517 us; speedup vs baseline: 1.0533x; 1.0272x over previous
//
#include <hip/hip_runtime.h>

#define N_NODES 50000
#define N_PAD   50048   // multiple of 64; pad rows garbage, never consumed
#define N_EDGES 800000
#define N_GRAPHS 500
#define DIM 128
#define EDIM 7
#define LAYERS 5
#define NCLASS 10
#define BN_EPS 1e-5f
#define TM 64           // GEMM tile rows (R12 measured-best config)
#define AST 264         // LDS A row stride (ushort): 528 B = odd 16B multiple -> conflict-free b128
#define NSB ((N_NODES + 256) / 256)   // 196 scan blocks

typedef __attribute__((ext_vector_type(8))) short bf16x8;
typedef __attribute__((ext_vector_type(4))) float f32x4;
typedef _Float16 h2 __attribute__((ext_vector_type(2)));

struct __align__(32) ERec { uint4 ea; int src; int pad0, pad1, pad2; };

__device__ __forceinline__ unsigned short f2bf(float f) {
    unsigned u = __float_as_uint(f);
    u = u + 0x7fffu + ((u >> 16) & 1u);   // RNE
    return (unsigned short)(u >> 16);
}
__device__ __forceinline__ float bf2f(unsigned short h) {
    return __uint_as_float(((unsigned)h) << 16);
}
__device__ __forceinline__ h2 u2h2(unsigned u) {
    union { unsigned u; h2 h; } c; c.u = u; return c.h;
}
__device__ __forceinline__ unsigned h22u(h2 h) {
    union { h2 h; unsigned u; } c; c.h = h; return c.u;
}
__device__ __forceinline__ unsigned packh2(float a, float b) {
    h2 h; h.x = (_Float16)a; h.y = (_Float16)b;   // RNE casts
    return h22u(h);
}

// ---------------- CSR build ----------------

__global__ void zero_ints(int* __restrict__ p, int n) {
    int i = blockIdx.x * 256 + threadIdx.x;
    if (i < n) p[i] = 0;
}

__global__ void hist_kernel(const int* __restrict__ dst, int* __restrict__ deg) {
    int e = blockIdx.x * 256 + threadIdx.x;
    if (e < N_EDGES) atomicAdd(&deg[dst[e]], 1);
}

__global__ __launch_bounds__(256)
void scan1(const int* __restrict__ deg, int* __restrict__ ro, int* __restrict__ bsums) {
    __shared__ int ws[4];
    int t = threadIdx.x;
    int i = blockIdx.x * 256 + t;
    int v = (i < N_NODES) ? deg[i] : 0;
    int lane = t & 63, wv = t >> 6;
    int s = v;
    #pragma unroll
    for (int off = 1; off < 64; off <<= 1) {
        int u = __shfl_up(s, off, 64);
        if (lane >= off) s += u;
    }
    if (lane == 63) ws[wv] = s;
    __syncthreads();
    if (t == 0) {
        int a = 0;
        #pragma unroll
        for (int k = 0; k < 4; ++k) { int x = ws[k]; ws[k] = a; a += x; }
        bsums[blockIdx.x] = a;
    }
    __syncthreads();
    int excl = s - v + ws[wv];
    if (i <= N_NODES) ro[i] = excl;
}

__global__ __launch_bounds__(256)
void scan2(int* __restrict__ bsums) {
    __shared__ int ws[4];
    int t = threadIdx.x;
    int v = (t < NSB) ? bsums[t] : 0;
    int lane = t & 63, wv = t >> 6;
    int s = v;
    #pragma unroll
    for (int off = 1; off < 64; off <<= 1) {
        int u = __shfl_up(s, off, 64);
        if (lane >= off) s += u;
    }
    if (lane == 63) ws[wv] = s;
    __syncthreads();
    if (t == 0) {
        int a = 0;
        #pragma unroll
        for (int k = 0; k < 4; ++k) { int x = ws[k]; ws[k] = a; a += x; }
    }
    __syncthreads();
    if (t < NSB) bsums[t] = s - v + ws[wv];
}

__global__ __launch_bounds__(256)
void scan3(int* __restrict__ ro, const int* __restrict__ bsums, int* __restrict__ cursor) {
    int i = blockIdx.x * 256 + threadIdx.x;
    if (i <= N_NODES) {
        int r = ro[i] + bsums[i >> 8];
        ro[i] = r;
        if (i < N_NODES) cursor[i] = r;
    }
}

// single pass: sequential read of src/dst/edge_attr -> fp16, ONE scattered 32B
// record per edge (combined rec measured best — split arrays regressed, R14)
__global__ void fill_rec(const int* __restrict__ dst, const int* __restrict__ src,
                         const float* __restrict__ edge_attr,
                         int* __restrict__ cursor, ERec* __restrict__ rec) {
    int e = blockIdx.x * 256 + threadIdx.x;
    if (e < N_EDGES) {
        const float* ap = edge_attr + (size_t)e * EDIM;
        uint4 ea;
        ea.x = packh2(ap[0], ap[1]);
        ea.y = packh2(ap[2], ap[3]);
        ea.z = packh2(ap[4], ap[5]);
        ea.w = packh2(ap[6], 0.f);
        int s = src[e];
        int pos = atomicAdd(&cursor[dst[e]], 1);
        rec[pos].ea = ea;
        rec[pos].src = s;
    }
}

// ---------------- one-time preps ----------------

__global__ void init_x(float* __restrict__ x, unsigned short* __restrict__ xb,
                       const float* __restrict__ emb) {
    int i = blockIdx.x * 256 + threadIdx.x;
    if (i < N_NODES * DIM) {
        float v = emb[i & (DIM - 1)];
        x[i] = v;
        xb[i] = f2bf(v);
    }
}

// W [k][n] fp32 -> transposed hi/lo bf16 Wt[m][n][k]
__global__ void prep_w(const float* __restrict__ W1, const float* __restrict__ W2,
                       unsigned short* __restrict__ Wthi, unsigned short* __restrict__ Wtlo) {
    int i = blockIdx.x * 256 + threadIdx.x;
    if (i >= 2 * LAYERS * DIM * DIM) return;
    int m = i >> 14;
    int n = i & 127;
    int k = (i >> 7) & 127;
    const float* W = (m < LAYERS) ? (W1 + (size_t)m * DIM * DIM)
                                  : (W2 + (size_t)(m - LAYERS) * DIM * DIM);
    float v = W[k * DIM + n];
    unsigned short hi = f2bf(v);
    float lo = v - bf2f(hi);
    size_t o = ((size_t)m << 14) + (size_t)n * DIM + k;
    Wthi[o] = hi;
    Wtlo[o] = f2bf(lo);
}

// ---------------- aggregation: one wave per node, 8-edge unroll ----------------
// rec/row_off wave-uniform -> scalar loads; xb gather = one coalesced 4B/lane
// load (256B row). 8 row-gathers in flight per wave (R15's 2 was the
// concurrency limiter: 2.6 TB/s ~= Little's law at 2 x 256B/wave).

#if __has_builtin(__builtin_amdgcn_fdot2)
#define HAVE_FDOT2 1
#else
#define HAVE_FDOT2 0
#endif

__device__ __forceinline__ void edge_accum2(float& acc0, float& acc1,
                                            uint4 eav, unsigned xv,
                                            const unsigned* Wp0, const unsigned* Wp1,
                                            float b0, float b1) {
    float e0 = b0, e1 = b1;
#if HAVE_FDOT2
    e0 = __builtin_amdgcn_fdot2(u2h2(eav.x), u2h2(Wp0[0]), e0, false);
    e0 = __builtin_amdgcn_fdot2(u2h2(eav.y), u2h2(Wp0[1]), e0, false);
    e0 = __builtin_amdgcn_fdot2(u2h2(eav.z), u2h2(Wp0[2]), e0, false);
    e0 = __builtin_amdgcn_fdot2(u2h2(eav.w), u2h2(Wp0[3]), e0, false);
    e1 = __builtin_amdgcn_fdot2(u2h2(eav.x), u2h2(Wp1[0]), e1, false);
    e1 = __builtin_amdgcn_fdot2(u2h2(eav.y), u2h2(Wp1[1]), e1, false);
    e1 = __builtin_amdgcn_fdot2(u2h2(eav.z), u2h2(Wp1[2]), e1, false);
    e1 = __builtin_amdgcn_fdot2(u2h2(eav.w), u2h2(Wp1[3]), e1, false);
#else
    h2 ea01 = u2h2(eav.x), ea23 = u2h2(eav.y), ea45 = u2h2(eav.z), ea67 = u2h2(eav.w);
    float a[8] = {(float)ea01.x, (float)ea01.y, (float)ea23.x, (float)ea23.y,
                  (float)ea45.x, (float)ea45.y, (float)ea67.x, 0.f};
    #pragma unroll
    for (int kp = 0; kp < 4; ++kp) {
        h2 w0 = u2h2(Wp0[kp]), w1 = u2h2(Wp1[kp]);
        e0 += a[kp * 2] * (float)w0.x + a[kp * 2 + 1] * (float)w0.y;
        e1 += a[kp * 2] * (float)w1.x + a[kp * 2 + 1] * (float)w1.y;
    }
#endif
    acc0 += fmaxf(__uint_as_float(xv << 16)         + e0, 0.f);
    acc1 += fmaxf(__uint_as_float(xv & 0xffff0000u) + e1, 0.f);
}

__global__ __launch_bounds__(256, 8)
void aggregate(const float* __restrict__ x, const unsigned short* __restrict__ xb,
               float* __restrict__ h,
               const ERec* __restrict__ rec,
               const int* __restrict__ row_off,
               const float* __restrict__ eW, const float* __restrict__ eb) {
    int t = threadIdx.x;
    int wv = __builtin_amdgcn_readfirstlane(t >> 6);  // wave id in block (uniform)
    int lane = t & 63;
    int c0 = lane * 2;
    int n = blockIdx.x * 4 + wv;                      // node for this wave (uniform)

    // Wp{0,1}[kp] = (W[2kp][c0+d], W[2kp+1][c0+d]) fp16 pairs; k=7 padded 0
    unsigned Wp0[4], Wp1[4];
    #pragma unroll
    for (int kp = 0; kp < 4; ++kp) {
        float w00 = eW[(kp * 2) * DIM + c0];
        float w01 = (kp * 2 + 1 < EDIM) ? eW[(kp * 2 + 1) * DIM + c0] : 0.f;
        float w10 = eW[(kp * 2) * DIM + c0 + 1];
        float w11 = (kp * 2 + 1 < EDIM) ? eW[(kp * 2 + 1) * DIM + c0 + 1] : 0.f;
        Wp0[kp] = packh2(w00, w01);
        Wp1[kp] = packh2(w10, w11);
    }
    float b0 = eb[c0], b1 = eb[c0 + 1];
    #pragma unroll
    for (int k = 0; k < 4; ++k) asm volatile("" : "+v"(Wp0[k]), "+v"(Wp1[k]));
    asm volatile("" : "+v"(b0), "+v"(b1));

    float acc0 = x[(size_t)n * DIM + c0];
    float acc1 = x[(size_t)n * DIM + c0 + 1];
    int idx = row_off[n], end = row_off[n + 1];       // uniform -> s_load

    // 8-edge unroll: 8 row-gathers in flight per wave
    for (; idx + 8 <= end; idx += 8) {
        ERec r[8];
        #pragma unroll
        for (int j = 0; j < 8; ++j) r[j] = rec[idx + j];          // scalar loads
        unsigned xv[8];
        #pragma unroll
        for (int j = 0; j < 8; ++j)
            xv[j] = *reinterpret_cast<const unsigned*>(xb + (size_t)r[j].src * DIM + c0);
        #pragma unroll
        for (int j = 0; j < 8; ++j)
            edge_accum2(acc0, acc1, r[j].ea, xv[j], Wp0, Wp1, b0, b1);
    }
    // tail (<8 edges)
    for (; idx < end; ++idx) {
        ERec r0 = rec[idx];
        unsigned xv0 = *reinterpret_cast<const unsigned*>(xb + (size_t)r0.src * DIM + c0);
        edge_accum2(acc0, acc1, r0.ea, xv0, Wp0, Wp1, b0, b1);
    }

    float2 o; o.x = acc0; o.y = acc1;
    *reinterpret_cast<float2*>(h + (size_t)n * DIM + c0) = o;
}

// ---------------- fused double MFMA GEMM (R12 measured-best: TM=64, persistent B) ----------------

__global__ __launch_bounds__(256)
void gemm2x(const float* __restrict__ in, float* __restrict__ outx,
            unsigned short* __restrict__ xb_out,
            const unsigned short* __restrict__ W1hi, const unsigned short* __restrict__ W1lo,
            const unsigned short* __restrict__ W2hi, const unsigned short* __restrict__ W2lo,
            const float* __restrict__ b1,
            const float* __restrict__ bn1g, const float* __restrict__ bn1b,
            const float* __restrict__ bn1m, const float* __restrict__ bn1v,
            const float* __restrict__ b2,
            const float* __restrict__ bn2g, const float* __restrict__ bn2b,
            const float* __restrict__ bn2m, const float* __restrict__ bn2v) {
    __shared__ __align__(16) unsigned short A2[TM * AST];   // 33792 B
    int t = threadIdx.x;
    int r0 = blockIdx.x * TM;
    int w = t >> 6;
    int lane = t & 63;
    int q = lane >> 4;
    int l16 = lane & 15;

    // B1 register fragments (in flight during A staging)
    bf16x8 bh[2][4], bl[2][4];
    #pragma unroll
    for (int nt = 0; nt < 2; ++nt) {
        int n = w * 32 + nt * 16 + l16;
        const bf16x8* gh = reinterpret_cast<const bf16x8*>(W1hi + (size_t)n * DIM);
        const bf16x8* gl = reinterpret_cast<const bf16x8*>(W1lo + (size_t)n * DIM);
        #pragma unroll
        for (int kc = 0; kc < 4; ++kc) {
            bh[nt][kc] = gh[kc * 4 + q];
            bl[nt][kc] = gl[kc * 4 + q];
        }
    }

    // stage A (hi/lo split)
    #pragma unroll
    for (int i = 0; i < 8; ++i) {
        int idx = t + i * 256;
        int row = idx >> 5;
        int kp = (idx & 31) * 4;
        float4 v = reinterpret_cast<const float4*>(in + (size_t)r0 * DIM)[idx];
        unsigned short h0 = f2bf(v.x), h1 = f2bf(v.y), h2_ = f2bf(v.z), h3 = f2bf(v.w);
        ushort4 hv; hv.x = h0; hv.y = h1; hv.z = h2_; hv.w = h3;
        ushort4 lv;
        lv.x = f2bf(v.x - bf2f(h0)); lv.y = f2bf(v.y - bf2f(h1));
        lv.z = f2bf(v.z - bf2f(h2_)); lv.w = f2bf(v.w - bf2f(h3));
        *reinterpret_cast<ushort4*>(&A2[row * AST + kp]) = hv;
        *reinterpret_cast<ushort4*>(&A2[row * AST + 128 + kp]) = lv;
    }
    __syncthreads();

    f32x4 acc[4][2];
    #pragma unroll
    for (int mt = 0; mt < 4; ++mt)
        #pragma unroll
        for (int nt = 0; nt < 2; ++nt)
            acc[mt][nt] = (f32x4){0.f, 0.f, 0.f, 0.f};

    #pragma unroll
    for (int kc = 0; kc < 4; ++kc) {
        bf16x8 ahi[4], alo[4];
        #pragma unroll
        for (int mt = 0; mt < 4; ++mt) {
            ahi[mt] = *reinterpret_cast<const bf16x8*>(&A2[(mt * 16 + l16) * AST + kc * 32 + q * 8]);
            alo[mt] = *reinterpret_cast<const bf16x8*>(&A2[(mt * 16 + l16) * AST + 128 + kc * 32 + q * 8]);
        }
        #pragma unroll
        for (int mt = 0; mt < 4; ++mt)
            #pragma unroll
            for (int nt = 0; nt < 2; ++nt) {
                acc[mt][nt] = __builtin_amdgcn_mfma_f32_16x16x32_bf16(ahi[mt], bh[nt][kc], acc[mt][nt], 0, 0, 0);
                acc[mt][nt] = __builtin_amdgcn_mfma_f32_16x16x32_bf16(ahi[mt], bl[nt][kc], acc[mt][nt], 0, 0, 0);
                acc[mt][nt] = __builtin_amdgcn_mfma_f32_16x16x32_bf16(alo[mt], bh[nt][kc], acc[mt][nt], 0, 0, 0);
            }
    }
    __syncthreads();   // all Kloop1 reads done before A2 overwrite

    // B2 fragments issued FIRST: latency hides under epilogue-1 VALU+LDS
    #pragma unroll
    for (int nt = 0; nt < 2; ++nt) {
        int n = w * 32 + nt * 16 + l16;
        const bf16x8* gh = reinterpret_cast<const bf16x8*>(W2hi + (size_t)n * DIM);
        const bf16x8* gl = reinterpret_cast<const bf16x8*>(W2lo + (size_t)n * DIM);
        #pragma unroll
        for (int kc = 0; kc < 4; ++kc) {
            bh[nt][kc] = gh[kc * 4 + q];
            bl[nt][kc] = gl[kc * 4 + q];
        }
    }

    // epilogue 1: bias + BN1 + ReLU -> back into A2 (hi/lo), local rows
    #pragma unroll
    for (int nt = 0; nt < 2; ++nt) {
        int col = w * 32 + nt * 16 + l16;
        float bias = b1[col];
        float sc = bn1g[col] * rsqrtf(bn1v[col] + BN_EPS);
        float sh = bn1b[col] - bn1m[col] * sc;
        #pragma unroll
        for (int mt = 0; mt < 4; ++mt) {
            #pragma unroll
            for (int r = 0; r < 4; ++r) {
                int rowl = mt * 16 + q * 4 + r;
                float o = fmaxf((acc[mt][nt][r] + bias) * sc + sh, 0.f);
                unsigned short hi = f2bf(o);
                A2[rowl * AST + col] = hi;
                A2[rowl * AST + 128 + col] = f2bf(o - bf2f(hi));
            }
        }
    }
    __syncthreads();

    #pragma unroll
    for (int mt = 0; mt < 4; ++mt)
        #pragma unroll
        for (int nt = 0; nt < 2; ++nt)
            acc[mt][nt] = (f32x4){0.f, 0.f, 0.f, 0.f};

    #pragma unroll
    for (int kc = 0; kc < 4; ++kc) {
        bf16x8 ahi[4], alo[4];
        #pragma unroll
        for (int mt = 0; mt < 4; ++mt) {
            ahi[mt] = *reinterpret_cast<const bf16x8*>(&A2[(mt * 16 + l16) * AST + kc * 32 + q * 8]);
            alo[mt] = *reinterpret_cast<const bf16x8*>(&A2[(mt * 16 + l16) * AST + 128 + kc * 32 + q * 8]);
        }
        #pragma unroll
        for (int mt = 0; mt < 4; ++mt)
            #pragma unroll
            for (int nt = 0; nt < 2; ++nt) {
                acc[mt][nt] = __builtin_amdgcn_mfma_f32_16x16x32_bf16(ahi[mt], bh[nt][kc], acc[mt][nt], 0, 0, 0);
                acc[mt][nt] = __builtin_amdgcn_mfma_f32_16x16x32_bf16(ahi[mt], bl[nt][kc], acc[mt][nt], 0, 0, 0);
                acc[mt][nt] = __builtin_amdgcn_mfma_f32_16x16x32_bf16(alo[mt], bh[nt][kc], acc[mt][nt], 0, 0, 0);
            }
    }

    // epilogue 2: bias + BN2 + ReLU -> x + xb
    #pragma unroll
    for (int nt = 0; nt < 2; ++nt) {
        int col = w * 32 + nt * 16 + l16;
        float bias = b2[col];
        float sc = bn2g[col] * rsqrtf(bn2v[col] + BN_EPS);
        float sh = bn2b[col] - bn2m[col] * sc;
        #pragma unroll
        for (int mt = 0; mt < 4; ++mt) {
            #pragma unroll
            for (int r = 0; r < 4; ++r) {
                int row = r0 + mt * 16 + q * 4 + r;
                float o = fmaxf((acc[mt][nt][r] + bias) * sc + sh, 0.f);
                outx[(size_t)row * DIM + col] = o;
                xb_out[(size_t)row * DIM + col] = f2bf(o);
            }
        }
    }
}

// ---------------- global mean pool (batch sorted) ----------------

__global__ __launch_bounds__(256)
void pool_kernel(const float* __restrict__ x, const int* __restrict__ batch,
                 float* __restrict__ g) {
    __shared__ float sh[256];
    __shared__ int sb[2];
    int gid = blockIdx.x;
    int t = threadIdx.x;
    if (t < 2) {
        int tgt = gid + t;
        int lo = 0, hi = N_NODES;
        while (lo < hi) { int mid = (lo + hi) >> 1; if (batch[mid] < tgt) lo = mid + 1; else hi = mid; }
        sb[t] = lo;
    }
    __syncthreads();
    int lo = sb[0], hi = sb[1];
    int d = t & 127, half = t >> 7;
    float a = 0.f;
    for (int n = lo + half; n < hi; n += 2) a += x[(size_t)n * DIM + d];
    sh[t] = a;
    __syncthreads();
    if (t < DIM) {
        float cnt = fmaxf((float)(hi - lo), 1.f);
        g[gid * DIM + t] = (sh[t] + sh[t + 128]) / cnt;
    }
}

// ---------------- head ----------------

__global__ __launch_bounds__(128)
void head1_kernel(const float* __restrict__ g, const float* __restrict__ W1,
                  const float* __restrict__ b1, float* __restrict__ h1) {
    __shared__ float gs[DIM];
    int gid = blockIdx.x, c = threadIdx.x;
    gs[c] = g[gid * DIM + c];
    __syncthreads();
    float acc = b1[c];
    for (int k = 0; k < DIM; ++k) acc += gs[k] * W1[k * DIM + c];
    h1[gid * DIM + c] = fmaxf(acc, 0.f);
}

__global__ __launch_bounds__(64)
void head2_kernel(const float* __restrict__ h1, const float* __restrict__ W2,
                  const float* __restrict__ b2, float* __restrict__ out) {
    __shared__ float hs[DIM];
    int gid = blockIdx.x;
    int t = threadIdx.x;
    hs[t] = h1[gid * DIM + t];
    hs[t + 64] = h1[gid * DIM + t + 64];
    __syncthreads();
    if (t < NCLASS) {
        float acc = b2[t];
        for (int k = 0; k < DIM; ++k) acc += hs[k] * W2[k * NCLASS + t];
        out[gid * NCLASS + t] = acc;
    }
}

// ---------------- launch ----------------

extern "C" void kernel_launch(void* const* d_in, const int* in_sizes, int n_in,
                              void* d_out, int out_size, void* d_ws, size_t ws_size,
                              hipStream_t stream) {
    const float* edge_attr = (const float*)d_in[0];
    const int*   edge_index = (const int*)d_in[1];
    const int*   batch = (const int*)d_in[2];
    const float* node_emb = (const float*)d_in[3];
    const float* edge_W = (const float*)d_in[4];
    const float* edge_b = (const float*)d_in[5];
    const float* mlp_W1 = (const float*)d_in[6];
    const float* mlp_b1 = (const float*)d_in[7];
    const float* bn1_g = (const float*)d_in[8];
    const float* bn1_b = (const float*)d_in[9];
    const float* bn1_m = (const float*)d_in[10];
    const float* bn1_v = (const float*)d_in[11];
    const float* mlp_W2 = (const float*)d_in[12];
    const float* mlp_b2 = (const float*)d_in[13];
    const float* bn2_g = (const float*)d_in[14];
    const float* bn2_b = (const float*)d_in[15];
    const float* bn2_m = (const float*)d_in[16];
    const float* bn2_v = (const float*)d_in[17];
    const float* head_W1 = (const float*)d_in[18];
    const float* head_b1 = (const float*)d_in[19];
    const float* head_W2 = (const float*)d_in[20];
    const float* head_b2 = (const float*)d_in[21];
    float* out = (float*)d_out;

    const int* src = edge_index;
    const int* dst = edge_index + N_EDGES;

    size_t off = 0;
    auto carve = [&](size_t bytes) {
        void* p = (char*)d_ws + off;
        off += (bytes + 255) & ~(size_t)255;
        return p;
    };
    float* x            = (float*)carve((size_t)N_PAD * DIM * 4);
    unsigned short* xb  = (unsigned short*)carve((size_t)N_PAD * DIM * 2);
    float* h            = (float*)carve((size_t)N_PAD * DIM * 4);
    ERec* rec           = (ERec*)carve((size_t)N_EDGES * sizeof(ERec));
    unsigned short* Wthi = (unsigned short*)carve((size_t)2 * LAYERS * DIM * DIM * 2);
    unsigned short* Wtlo = (unsigned short*)carve((size_t)2 * LAYERS * DIM * DIM * 2);
    int* deg      = (int*)carve((size_t)N_NODES * 4);
    int* row_off  = (int*)carve((size_t)(N_NODES + 1) * 4);
    int* cursor   = (int*)carve((size_t)N_NODES * 4);
    int* bsums    = (int*)carve((size_t)NSB * 4);
    float* gbuf   = (float*)carve((size_t)N_GRAPHS * DIM * 4);
    float* h1buf  = (float*)carve((size_t)N_GRAPHS * DIM * 4);
    (void)ws_size;

    // CSR build + single-pass edge scatter
    zero_ints<<<(N_NODES + 255) / 256, 256, 0, stream>>>(deg, N_NODES);
    hist_kernel<<<(N_EDGES + 255) / 256, 256, 0, stream>>>(dst, deg);
    scan1<<<NSB, 256, 0, stream>>>(deg, row_off, bsums);
    scan2<<<1, 256, 0, stream>>>(bsums);
    scan3<<<NSB, 256, 0, stream>>>(row_off, bsums, cursor);
    fill_rec<<<(N_EDGES + 255) / 256, 256, 0, stream>>>(dst, src, edge_attr, cursor, rec);

    init_x<<<(N_NODES * DIM + 255) / 256, 256, 0, stream>>>(x, xb, node_emb);
    prep_w<<<(2 * LAYERS * DIM * DIM + 255) / 256, 256, 0, stream>>>(mlp_W1, mlp_W2, Wthi, Wtlo);

    const int gemm_blocks = N_PAD / TM;   // 782
    for (int l = 0; l < LAYERS; ++l) {
        aggregate<<<N_NODES / 4, 256, 0, stream>>>(
            x, xb, h, rec, row_off,
            edge_W + (size_t)l * EDIM * DIM, edge_b + (size_t)l * DIM);
        gemm2x<<<gemm_blocks, 256, 0, stream>>>(
            h, x, xb,
            Wthi + ((size_t)l << 14), Wtlo + ((size_t)l << 14),
            Wthi + ((size_t)(LAYERS + l) << 14), Wtlo + ((size_t)(LAYERS + l) << 14),
            mlp_b1 + (size_t)l * DIM,
            bn1_g + (size_t)l * DIM, bn1_b + (size_t)l * DIM,
            bn1_m + (size_t)l * DIM, bn1_v + (size_t)l * DIM,
            mlp_b2 + (size_t)l * DIM,
            bn2_g + (size_t)l * DIM, bn2_b + (size_t)l * DIM,
            bn2_m + (size_t)l * DIM, bn2_v + (size_t)l * DIM);
    }

    pool_kernel<<<N_GRAPHS, 256, 0, stream>>>(x, batch, gbuf);
    head1_kernel<<<N_GRAPHS, 128, 0, stream>>>(gbuf, head_W1, head_b1, h1buf);
    head2_kernel<<<N_GRAPHS, 64, 0, stream>>>(h1buf, head_W2, head_b2, out);
}